// Round 4
// baseline (848.395 us; speedup 1.0000x reference)
//
#include <hip/hip_runtime.h>

#define NN 100000
#define NE 3200000
#define NR 8
#define NBUK 6250          // dst>>4 buckets (16 nodes each)

// ---------- coarse histogram: bucket = dst>>4 ----------
__global__ void coarse_hist(const int* __restrict__ dst, int* __restrict__ ccnt) {
    int e = blockIdx.x * blockDim.x + threadIdx.x;
    if (e < NE) atomicAdd(&ccnt[dst[e] >> 4], 1);
}

// ---------- single-block exclusive scan over ccnt[NBUK] -> coff[NBUK+1] ----------
__global__ void coarse_scan(const int* __restrict__ ccnt, int* __restrict__ coff) {
    __shared__ int s[1024];
    __shared__ int sbase;
    int t = threadIdx.x;
    if (t == 0) sbase = 0;
    __syncthreads();
    for (int c = 0; c < (NBUK + 1023) / 1024; c++) {
        int idx = c * 1024 + t;
        int v = (idx < NBUK) ? ccnt[idx] : 0;
        s[t] = v; __syncthreads();
        for (int o = 1; o < 1024; o <<= 1) {
            int u = (t >= o) ? s[t - o] : 0;
            __syncthreads();
            s[t] += u;
            __syncthreads();
        }
        if (idx < NBUK) coff[idx] = sbase + s[t] - v;
        __syncthreads();
        if (t == 0) sbase += s[1023];
        __syncthreads();
    }
    if (t == 0) coff[NBUK] = sbase;   // == NE
}

// ---------- pass 1: scatter (dst, et<<17|src) pairs into coarse buckets ----------
__global__ void pass1(const int* __restrict__ src, const int* __restrict__ dst,
                      const int* __restrict__ et, const int* __restrict__ coff,
                      int* __restrict__ cfill, uint2* __restrict__ pairs) {
    int e = blockIdx.x * blockDim.x + threadIdx.x;
    if (e >= NE) return;
    int d = dst[e];
    int b = d >> 4;
    int pos = coff[b] + atomicAdd(&cfill[b], 1);
    pairs[pos] = make_uint2((unsigned)d, ((unsigned)et[e] << 17) | (unsigned)src[e]);
}

// ---------- pass 2: per-bucket local sort by node; writes epk + CSR off ----------
__global__ __launch_bounds__(256) void pass2(const uint2* __restrict__ pairs,
                                             const int* __restrict__ coff,
                                             unsigned* __restrict__ epk,
                                             int* __restrict__ off) {
    __shared__ int lcnt[16];
    __shared__ int lfill[16];
    __shared__ int lscan[16];
    int b = blockIdx.x, t = threadIdx.x;
    int base = coff[b], end = coff[b + 1];
    if (t < 16) { lcnt[t] = 0; lfill[t] = 0; }
    __syncthreads();
    for (int e = base + t; e < end; e += 256)
        atomicAdd(&lcnt[pairs[e].x & 15], 1);
    __syncthreads();
    if (t == 0) {
        int run = 0;
        for (int d = 0; d < 16; d++) {
            lscan[d] = run;
            off[b * 16 + d] = base + run;
            run += lcnt[d];
        }
        if (b == NBUK - 1) off[NN] = NE;
    }
    __syncthreads();
    for (int e = base + t; e < end; e += 256) {
        uint2 u = pairs[e];
        int d = u.x & 15;
        int p = atomicAdd(&lfill[d], 1);
        epk[base + lscan[d] + p] = u.y;
    }
}

// ---------- Layer 1 fused: gather-mean (per-rel via predication) + root + matmuls + ReLU
// block = 256 threads = 16 nodes x 16 feature-lanes
__global__ __launch_bounds__(256, 8) void l1_fused(
        const float* __restrict__ x, const unsigned* __restrict__ epk,
        const int* __restrict__ off,
        const float* __restrict__ W1, const float* __restrict__ root1,
        const float* __restrict__ b1, float* __restrict__ h) {
    __shared__ float sAgg[16][NR * 16 + 8];
    int nl = threadIdx.x >> 4, k = threadIdx.x & 15;
    int i = blockIdx.x * 16 + nl;
    int s0 = off[i], e1 = off[i + 1];

    float acc[NR];
#pragma unroll
    for (int r = 0; r < NR; r++) acc[r] = 0.0f;
    unsigned long long cp = 0;

    for (int e0 = s0; e0 < e1; e0 += 4) {
        unsigned u0 = epk[min(e0 + 0, NE - 1)];
        unsigned u1 = epk[min(e0 + 1, NE - 1)];
        unsigned u2 = epk[min(e0 + 2, NE - 1)];
        unsigned u3 = epk[min(e0 + 3, NE - 1)];
        float v0 = x[(u0 & 0x1FFFF) * 16 + k];
        float v1 = x[(u1 & 0x1FFFF) * 16 + k];
        float v2 = x[(u2 & 0x1FFFF) * 16 + k];
        float v3 = x[(u3 & 0x1FFFF) * 16 + k];
        int r0 = u0 >> 17, r1 = u1 >> 17, r2 = u2 >> 17, r3 = u3 >> 17;
        bool m0 = e0 + 0 < e1, m1 = e0 + 1 < e1, m2 = e0 + 2 < e1, m3 = e0 + 3 < e1;
        v0 = m0 ? v0 : 0.0f; v1 = m1 ? v1 : 0.0f;
        v2 = m2 ? v2 : 0.0f; v3 = m3 ? v3 : 0.0f;
#pragma unroll
        for (int r = 0; r < NR; r++) {
            acc[r] += (r0 == r ? v0 : 0.0f);
            acc[r] += (r1 == r ? v1 : 0.0f);
            acc[r] += (r2 == r ? v2 : 0.0f);
            acc[r] += (r3 == r ? v3 : 0.0f);
        }
        cp += (m0 ? 1ull << (r0 * 8) : 0ull);
        cp += (m1 ? 1ull << (r1 * 8) : 0ull);
        cp += (m2 ? 1ull << (r2 * 8) : 0ull);
        cp += (m3 ? 1ull << (r3 * 8) : 0ull);
    }
#pragma unroll
    for (int r = 0; r < NR; r++) {
        int c = (int)((cp >> (r * 8)) & 0xFF);
        sAgg[nl][r * 16 + k] = acc[r] * (1.0f / (float)(c > 1 ? c : 1));
    }
    __syncthreads();
    // 512 outputs (16 nodes x 32), 2 per thread; W1/root1/b1 via L1 (hot)
#pragma unroll
    for (int ph = 0; ph < 2; ph++) {
        int idx = ph * 256 + threadIdx.x;
        int n2 = idx >> 5, o = idx & 31;
        int ii = blockIdx.x * 16 + n2;
        float a = b1[o];
        const float* xi = x + ii * 16;
#pragma unroll
        for (int kk = 0; kk < 16; kk++) a += xi[kk] * root1[kk * 32 + o];
#pragma unroll
        for (int r = 0; r < NR; r++)
#pragma unroll
            for (int kk = 0; kk < 16; kk++)
                a += sAgg[n2][r * 16 + kk] * W1[(r * 16 + kk) * 32 + o];
        h[ii * 32 + o] = fmaxf(a, 0.0f);
    }
}

// ---------- Layer 2 fused: gather-mean + root2 + matmuls ----------
// block = 256 threads = 8 nodes x 32 feature-lanes
__global__ __launch_bounds__(256, 8) void l2_fused(
        const float* __restrict__ h, const unsigned* __restrict__ epk,
        const int* __restrict__ off,
        const float* __restrict__ W2, const float* __restrict__ root2,
        const float* __restrict__ b2, float* __restrict__ out) {
    __shared__ float sAgg[8][NR * 32 + 1];
    int nl = threadIdx.x >> 5, k = threadIdx.x & 31;
    int i = blockIdx.x * 8 + nl;
    int s0 = off[i], e1 = off[i + 1];

    float acc[NR];
#pragma unroll
    for (int r = 0; r < NR; r++) acc[r] = 0.0f;
    unsigned long long cp = 0;

    for (int e0 = s0; e0 < e1; e0 += 4) {
        unsigned u0 = epk[min(e0 + 0, NE - 1)];
        unsigned u1 = epk[min(e0 + 1, NE - 1)];
        unsigned u2 = epk[min(e0 + 2, NE - 1)];
        unsigned u3 = epk[min(e0 + 3, NE - 1)];
        float v0 = h[(u0 & 0x1FFFF) * 32 + k];
        float v1 = h[(u1 & 0x1FFFF) * 32 + k];
        float v2 = h[(u2 & 0x1FFFF) * 32 + k];
        float v3 = h[(u3 & 0x1FFFF) * 32 + k];
        int r0 = u0 >> 17, r1 = u1 >> 17, r2 = u2 >> 17, r3 = u3 >> 17;
        bool m0 = e0 + 0 < e1, m1 = e0 + 1 < e1, m2 = e0 + 2 < e1, m3 = e0 + 3 < e1;
        v0 = m0 ? v0 : 0.0f; v1 = m1 ? v1 : 0.0f;
        v2 = m2 ? v2 : 0.0f; v3 = m3 ? v3 : 0.0f;
#pragma unroll
        for (int r = 0; r < NR; r++) {
            acc[r] += (r0 == r ? v0 : 0.0f);
            acc[r] += (r1 == r ? v1 : 0.0f);
            acc[r] += (r2 == r ? v2 : 0.0f);
            acc[r] += (r3 == r ? v3 : 0.0f);
        }
        cp += (m0 ? 1ull << (r0 * 8) : 0ull);
        cp += (m1 ? 1ull << (r1 * 8) : 0ull);
        cp += (m2 ? 1ull << (r2 * 8) : 0ull);
        cp += (m3 ? 1ull << (r3 * 8) : 0ull);
    }
#pragma unroll
    for (int r = 0; r < NR; r++) {
        int c = (int)((cp >> (r * 8)) & 0xFF);
        sAgg[nl][r * 32 + k] = acc[r] * (1.0f / (float)(c > 1 ? c : 1));
    }
    __syncthreads();
    // per node: 16 outputs, k-sum split across lane halves; W2/root2/b2 via L1
    int o = k & 15, half = k >> 4;
    float a = 0.0f;
    const float* hi = h + i * 32;
#pragma unroll
    for (int kk = 0; kk < 16; kk++) {
        int kf = half * 16 + kk;
        a += hi[kf] * root2[kf * 16 + o];
    }
#pragma unroll
    for (int r = 0; r < NR; r++)
#pragma unroll
        for (int kk = 0; kk < 16; kk++) {
            int kf = half * 16 + kk;
            a += sAgg[nl][r * 32 + kf] * W2[(r * 32 + kf) * 16 + o];
        }
    float tot = a + __shfl_xor(a, 16);
    if (half == 0) out[i * 16 + o] = tot + b2[o];
}

extern "C" void kernel_launch(void* const* d_in, const int* in_sizes, int n_in,
                              void* d_out, int out_size, void* d_ws, size_t ws_size,
                              hipStream_t stream) {
    const float* x = (const float*)d_in[0];
    const int* ei = (const int*)d_in[1];
    const int* et = (const int*)d_in[2];
    const float* W1 = (const float*)d_in[3];
    const float* root1 = (const float*)d_in[4];
    const float* b1 = (const float*)d_in[5];
    const float* W2 = (const float*)d_in[6];
    const float* root2 = (const float*)d_in[7];
    const float* b2 = (const float*)d_in[8];
    float* out = (float*)d_out;
    const int* src = ei;
    const int* dst = ei + NE;

    char* ws = (char*)d_ws;
    int* off       = (int*)(ws + 0);            // (NN+1)*4   = 400,004 B
    int* ccnt      = (int*)(ws + 400016);       // 25,000 B
    int* cfill     = (int*)(ws + 425016);       // 25,000 B
    int* coff      = (int*)(ws + 450016);       // 25,004 B
    uint2* pairs   = (uint2*)(ws + 480000);     // 25.6 MB
    unsigned* epk  = (unsigned*)(ws + 26080000);// 12.8 MB
    float* h       = (float*)(ws + 38880000);   // 12.8 MB   (total ~51.7 MB)

    const int TPB = 256;
    hipMemsetAsync(ccnt, 0, 50000, stream);   // ccnt + cfill (contiguous)
    coarse_hist<<<(NE + TPB - 1) / TPB, TPB, 0, stream>>>(dst, ccnt);
    coarse_scan<<<1, 1024, 0, stream>>>(ccnt, coff);
    pass1<<<(NE + TPB - 1) / TPB, TPB, 0, stream>>>(src, dst, et, coff, cfill, pairs);
    pass2<<<NBUK, 256, 0, stream>>>(pairs, coff, epk, off);
    l1_fused<<<NN / 16, 256, 0, stream>>>(x, epk, off, W1, root1, b1, h);
    l2_fused<<<NN / 8, 256, 0, stream>>>(h, epk, off, W2, root2, b2, out);
}

// Round 5
// 531.615 us; speedup vs baseline: 1.5959x; 1.5959x over previous
//
#include <hip/hip_runtime.h>

#define NN 100000
#define NE 3200000
#define NR 8
#define NBUK 6250            // dst>>4 buckets (16 nodes each)
#define NCH 50               // edge-index chunks per bucket
#define CHSZ 64000           // NE / NCH exactly
#define NKC (NBUK * NCH)     // 312500 cells
#define SCAN_TPB 256
#define SCAN_EPB 1024
#define NB ((NKC + SCAN_EPB - 1) / SCAN_EPB)   // 306 blocks

// ---------- chunked coarse histogram: cell = (dst>>4)*NCH + e/CHSZ ----------
__global__ void chunk_hist(const int* __restrict__ dst, int* __restrict__ ccnt) {
    int e = blockIdx.x * blockDim.x + threadIdx.x;
    if (e < NE) {
        int cell = (dst[e] >> 4) * NCH + e / CHSZ;
        atomicAdd(&ccnt[cell], 1);
    }
}

// ---------- 3-kernel exclusive scan over ccnt[NKC] -> coff[NKC] ----------
__global__ void block_sums(const int* __restrict__ cnt, int* __restrict__ bsum) {
    __shared__ int s[SCAN_TPB];
    int base = blockIdx.x * SCAN_EPB;
    int t = threadIdx.x;
    int v = 0;
#pragma unroll
    for (int j = 0; j < 4; j++) {
        int idx = base + t * 4 + j;
        if (idx < NKC) v += cnt[idx];
    }
    s[t] = v; __syncthreads();
    for (int o = SCAN_TPB / 2; o > 0; o >>= 1) {
        if (t < o) s[t] += s[t + o];
        __syncthreads();
    }
    if (t == 0) bsum[blockIdx.x] = s[0];
}

__global__ void scan_sums(int* __restrict__ bsum) {  // single block, 1024 threads
    __shared__ int s[1024];
    int t = threadIdx.x;
    int v = (t < NB) ? bsum[t] : 0;
    s[t] = v; __syncthreads();
    for (int o = 1; o < 1024; o <<= 1) {
        int u = (t >= o) ? s[t - o] : 0;
        __syncthreads();
        s[t] += u;
        __syncthreads();
    }
    if (t < NB) bsum[t] = s[t] - v;  // exclusive
}

__global__ void block_scan(const int* __restrict__ cnt, const int* __restrict__ bsum,
                           int* __restrict__ off) {
    __shared__ int s[SCAN_TPB];
    int base = blockIdx.x * SCAN_EPB;
    int t = threadIdx.x;
    int v[4]; int sum = 0;
#pragma unroll
    for (int j = 0; j < 4; j++) {
        int idx = base + t * 4 + j;
        v[j] = (idx < NKC) ? cnt[idx] : 0;
        sum += v[j];
    }
    s[t] = sum; __syncthreads();
    int mine = sum;
    for (int o = 1; o < SCAN_TPB; o <<= 1) {
        int u = (t >= o) ? s[t - o] : 0;
        __syncthreads();
        s[t] += u;
        __syncthreads();
    }
    int ex = s[t] - mine + bsum[blockIdx.x];
#pragma unroll
    for (int j = 0; j < 4; j++) {
        int idx = base + t * 4 + j;
        if (idx < NKC) { off[idx] = ex; ex += v[j]; }
    }
}

// ---------- pass 1: scatter packed (dst&15)<<20 | et<<17 | src into cells ----------
__global__ void pass1(const int* __restrict__ src, const int* __restrict__ dst,
                      const int* __restrict__ et, const int* __restrict__ coff,
                      int* __restrict__ cfill, unsigned* __restrict__ pk) {
    int e = blockIdx.x * blockDim.x + threadIdx.x;
    if (e >= NE) return;
    int d = dst[e];
    int cell = (d >> 4) * NCH + e / CHSZ;
    int pos = coff[cell] + atomicAdd(&cfill[cell], 1);
    pk[pos] = ((unsigned)(d & 15) << 20) | ((unsigned)et[e] << 17) | (unsigned)src[e];
}

// ---------- pass 2: per-bucket fine sort by node; writes epk + CSR off ----------
__global__ __launch_bounds__(256) void pass2(const unsigned* __restrict__ pk,
                                             const int* __restrict__ coff,
                                             unsigned* __restrict__ epk,
                                             int* __restrict__ off) {
    __shared__ int lcnt[16];
    __shared__ int lfill[16];
    __shared__ int lscan[16];
    int b = blockIdx.x, t = threadIdx.x;
    int base = coff[b * NCH];
    int end = (b == NBUK - 1) ? NE : coff[(b + 1) * NCH];
    if (t < 16) { lcnt[t] = 0; lfill[t] = 0; }
    __syncthreads();
    for (int e = base + t; e < end; e += 256)
        atomicAdd(&lcnt[pk[e] >> 20], 1);
    __syncthreads();
    if (t == 0) {
        int run = 0;
        for (int d = 0; d < 16; d++) {
            lscan[d] = run;
            off[b * 16 + d] = base + run;
            run += lcnt[d];
        }
        if (b == NBUK - 1) off[NN] = NE;
    }
    __syncthreads();
    for (int e = base + t; e < end; e += 256) {
        unsigned u = pk[e];
        int d = u >> 20;
        int p = atomicAdd(&lfill[d], 1);
        epk[base + lscan[d] + p] = u;
    }
}

// ---------- Layer 1 fused: gather-mean (per-rel via predication) + root + matmuls + ReLU
// block = 256 threads = 16 nodes x 16 feature-lanes
__global__ __launch_bounds__(256, 8) void l1_fused(
        const float* __restrict__ x, const unsigned* __restrict__ epk,
        const int* __restrict__ off,
        const float* __restrict__ W1, const float* __restrict__ root1,
        const float* __restrict__ b1, float* __restrict__ h) {
    __shared__ float sAgg[16][NR * 16 + 8];
    int nl = threadIdx.x >> 4, k = threadIdx.x & 15;
    int i = blockIdx.x * 16 + nl;
    int s0 = off[i], e1 = off[i + 1];

    float acc[NR];
#pragma unroll
    for (int r = 0; r < NR; r++) acc[r] = 0.0f;
    unsigned long long cp = 0;

    for (int e0 = s0; e0 < e1; e0 += 4) {
        unsigned u0 = epk[min(e0 + 0, NE - 1)];
        unsigned u1 = epk[min(e0 + 1, NE - 1)];
        unsigned u2 = epk[min(e0 + 2, NE - 1)];
        unsigned u3 = epk[min(e0 + 3, NE - 1)];
        float v0 = x[(u0 & 0x1FFFF) * 16 + k];
        float v1 = x[(u1 & 0x1FFFF) * 16 + k];
        float v2 = x[(u2 & 0x1FFFF) * 16 + k];
        float v3 = x[(u3 & 0x1FFFF) * 16 + k];
        int r0 = (u0 >> 17) & 7, r1 = (u1 >> 17) & 7;
        int r2 = (u2 >> 17) & 7, r3 = (u3 >> 17) & 7;
        bool m0 = e0 + 0 < e1, m1 = e0 + 1 < e1, m2 = e0 + 2 < e1, m3 = e0 + 3 < e1;
        v0 = m0 ? v0 : 0.0f; v1 = m1 ? v1 : 0.0f;
        v2 = m2 ? v2 : 0.0f; v3 = m3 ? v3 : 0.0f;
#pragma unroll
        for (int r = 0; r < NR; r++) {
            acc[r] += (r0 == r ? v0 : 0.0f);
            acc[r] += (r1 == r ? v1 : 0.0f);
            acc[r] += (r2 == r ? v2 : 0.0f);
            acc[r] += (r3 == r ? v3 : 0.0f);
        }
        cp += (m0 ? 1ull << (r0 * 8) : 0ull);
        cp += (m1 ? 1ull << (r1 * 8) : 0ull);
        cp += (m2 ? 1ull << (r2 * 8) : 0ull);
        cp += (m3 ? 1ull << (r3 * 8) : 0ull);
    }
#pragma unroll
    for (int r = 0; r < NR; r++) {
        int c = (int)((cp >> (r * 8)) & 0xFF);
        sAgg[nl][r * 16 + k] = acc[r] * (1.0f / (float)(c > 1 ? c : 1));
    }
    __syncthreads();
    // 512 outputs (16 nodes x 32), 2 per thread; W1/root1/b1 via L1 (hot)
#pragma unroll
    for (int ph = 0; ph < 2; ph++) {
        int idx = ph * 256 + threadIdx.x;
        int n2 = idx >> 5, o = idx & 31;
        int ii = blockIdx.x * 16 + n2;
        float a = b1[o];
        const float* xi = x + ii * 16;
#pragma unroll
        for (int kk = 0; kk < 16; kk++) a += xi[kk] * root1[kk * 32 + o];
#pragma unroll
        for (int r = 0; r < NR; r++)
#pragma unroll
            for (int kk = 0; kk < 16; kk++)
                a += sAgg[n2][r * 16 + kk] * W1[(r * 16 + kk) * 32 + o];
        h[ii * 32 + o] = fmaxf(a, 0.0f);
    }
}

// ---------- Layer 2 fused: gather-mean + root2 + matmuls ----------
// block = 256 threads = 8 nodes x 32 feature-lanes
__global__ __launch_bounds__(256, 8) void l2_fused(
        const float* __restrict__ h, const unsigned* __restrict__ epk,
        const int* __restrict__ off,
        const float* __restrict__ W2, const float* __restrict__ root2,
        const float* __restrict__ b2, float* __restrict__ out) {
    __shared__ float sAgg[8][NR * 32 + 1];
    int nl = threadIdx.x >> 5, k = threadIdx.x & 31;
    int i = blockIdx.x * 8 + nl;
    int s0 = off[i], e1 = off[i + 1];

    float acc[NR];
#pragma unroll
    for (int r = 0; r < NR; r++) acc[r] = 0.0f;
    unsigned long long cp = 0;

    for (int e0 = s0; e0 < e1; e0 += 4) {
        unsigned u0 = epk[min(e0 + 0, NE - 1)];
        unsigned u1 = epk[min(e0 + 1, NE - 1)];
        unsigned u2 = epk[min(e0 + 2, NE - 1)];
        unsigned u3 = epk[min(e0 + 3, NE - 1)];
        float v0 = h[(u0 & 0x1FFFF) * 32 + k];
        float v1 = h[(u1 & 0x1FFFF) * 32 + k];
        float v2 = h[(u2 & 0x1FFFF) * 32 + k];
        float v3 = h[(u3 & 0x1FFFF) * 32 + k];
        int r0 = (u0 >> 17) & 7, r1 = (u1 >> 17) & 7;
        int r2 = (u2 >> 17) & 7, r3 = (u3 >> 17) & 7;
        bool m0 = e0 + 0 < e1, m1 = e0 + 1 < e1, m2 = e0 + 2 < e1, m3 = e0 + 3 < e1;
        v0 = m0 ? v0 : 0.0f; v1 = m1 ? v1 : 0.0f;
        v2 = m2 ? v2 : 0.0f; v3 = m3 ? v3 : 0.0f;
#pragma unroll
        for (int r = 0; r < NR; r++) {
            acc[r] += (r0 == r ? v0 : 0.0f);
            acc[r] += (r1 == r ? v1 : 0.0f);
            acc[r] += (r2 == r ? v2 : 0.0f);
            acc[r] += (r3 == r ? v3 : 0.0f);
        }
        cp += (m0 ? 1ull << (r0 * 8) : 0ull);
        cp += (m1 ? 1ull << (r1 * 8) : 0ull);
        cp += (m2 ? 1ull << (r2 * 8) : 0ull);
        cp += (m3 ? 1ull << (r3 * 8) : 0ull);
    }
#pragma unroll
    for (int r = 0; r < NR; r++) {
        int c = (int)((cp >> (r * 8)) & 0xFF);
        sAgg[nl][r * 32 + k] = acc[r] * (1.0f / (float)(c > 1 ? c : 1));
    }
    __syncthreads();
    // per node: 16 outputs, k-sum split across lane halves; W2/root2/b2 via L1
    int o = k & 15, half = k >> 4;
    float a = 0.0f;
    const float* hi = h + i * 32;
#pragma unroll
    for (int kk = 0; kk < 16; kk++) {
        int kf = half * 16 + kk;
        a += hi[kf] * root2[kf * 16 + o];
    }
#pragma unroll
    for (int r = 0; r < NR; r++)
#pragma unroll
        for (int kk = 0; kk < 16; kk++) {
            int kf = half * 16 + kk;
            a += sAgg[nl][r * 32 + kf] * W2[(r * 32 + kf) * 16 + o];
        }
    float tot = a + __shfl_xor(a, 16);
    if (half == 0) out[i * 16 + o] = tot + b2[o];
}

extern "C" void kernel_launch(void* const* d_in, const int* in_sizes, int n_in,
                              void* d_out, int out_size, void* d_ws, size_t ws_size,
                              hipStream_t stream) {
    const float* x = (const float*)d_in[0];
    const int* ei = (const int*)d_in[1];
    const int* et = (const int*)d_in[2];
    const float* W1 = (const float*)d_in[3];
    const float* root1 = (const float*)d_in[4];
    const float* b1 = (const float*)d_in[5];
    const float* W2 = (const float*)d_in[6];
    const float* root2 = (const float*)d_in[7];
    const float* b2 = (const float*)d_in[8];
    float* out = (float*)d_out;
    const int* src = ei;
    const int* dst = ei + NE;

    char* ws = (char*)d_ws;
    int* off       = (int*)(ws + 0);            // (NN+1)*4 = 400,004 B
    int* ccnt      = (int*)(ws + 400016);       // 1.25 MB
    int* cfill     = (int*)(ws + 1650016);      // 1.25 MB
    int* coff      = (int*)(ws + 2900016);      // 1.25 MB
    int* bsum      = (int*)(ws + 4150016);      // ~1.3 KB
    unsigned* pk   = (unsigned*)(ws + 4154112); // 12.8 MB
    unsigned* epk  = (unsigned*)(ws + 16954112);// 12.8 MB
    float* h       = (float*)(ws + 29754112);   // 12.8 MB  (total ~42.6 MB)

    const int TPB = 256;
    hipMemsetAsync(ccnt, 0, 2500000, stream);   // ccnt + cfill (contiguous)
    chunk_hist<<<(NE + TPB - 1) / TPB, TPB, 0, stream>>>(dst, ccnt);
    block_sums<<<NB, SCAN_TPB, 0, stream>>>(ccnt, bsum);
    scan_sums<<<1, 1024, 0, stream>>>(bsum);
    block_scan<<<NB, SCAN_TPB, 0, stream>>>(ccnt, bsum, coff);
    pass1<<<(NE + TPB - 1) / TPB, TPB, 0, stream>>>(src, dst, et, coff, cfill, pk);
    pass2<<<NBUK, 256, 0, stream>>>(pk, coff, epk, off);
    l1_fused<<<NN / 16, 256, 0, stream>>>(x, epk, off, W1, root1, b1, h);
    l2_fused<<<NN / 8, 256, 0, stream>>>(h, epk, off, W2, root2, b2, out);
}